// Round 9
// baseline (177.514 us; speedup 1.0000x reference)
//
#include <hip/hip_runtime.h>
#include <hip/hip_bf16.h>
#include <math.h>

#define B_DIM 8192
#define IN_F  1024
#define OUT_F 1024
#define NSTEP 160                    // 32 g-groups x 5 slabs (K=5120)
#define BTILE 4096                   // one B step-tile: 64 cols x 32 k x 2B
#define GBYTES (5 * BTILE)           // one g-group of B tiles: 20 KB

typedef unsigned short u16;
typedef unsigned int u32;
typedef __attribute__((ext_vector_type(8))) short bf16x8;
typedef __attribute__((ext_vector_type(8))) unsigned short u16x8;
typedef __attribute__((ext_vector_type(4))) float f32x4;

#define GLOBAL_AS __attribute__((address_space(1)))
#define LDS_AS    __attribute__((address_space(3)))

__device__ __forceinline__ void gload16(const void* g, void* l) {
    __builtin_amdgcn_global_load_lds((const GLOBAL_AS unsigned int*)g,
                                     (LDS_AS unsigned int*)l, 16, 0, 0);
}

__device__ __forceinline__ u16 f2bf(float v) {
    u32 u = __float_as_uint(v);
    return (u16)((u + 0x7FFFu + ((u >> 16) & 1u)) >> 16);
}

__device__ __forceinline__ u32 cvt_pk(float lo, float hi) {
    u32 r;
    asm("v_cvt_pk_bf16_f32 %0, %1, %2" : "=v"(r) : "v"(lo), "v"(hi));
    return r;
}

// ---------------------------------------------------------------------------
// B image, 16 panels of 64 cols, ordered by GEMM step t = g*5 + s:
//   s=0: bf16(base_weight), s=1..4: bf16(sw_s - sw_{s-1}).
// Tile byte = ((p*160 + g*5 + s)*4096) + sn*1024 + lane*16,
// p = o>>6 (panel), sn = (o>>4)&3, fc = o&15, q = lane>>4 k-octet.
// One g-group's 5 tiles are 20 KB contiguous -> 5 linear gload16/thread.
// ---------------------------------------------------------------------------
__global__ __launch_bounds__(256) void pack_B_kernel(
    const float* __restrict__ sw, const float* __restrict__ bw,
    char* __restrict__ Bt)
{
    int gid  = blockIdx.x * 256 + threadIdx.x;      // 131072 threads
    int lane = gid & 63;
    int wav  = gid >> 6;                            // 2048 waves
    int g    = wav & 31;
    int sn   = (wav >> 5) & 3;
    int p    = wav >> 7;                            // 0..15
    int fc   = lane & 15;
    int q    = lane >> 4;

    int o  = p * 64 + sn * 16 + fc;
    int i0 = g * 32 + q * 8;

    size_t tb = ((size_t)(p * 160 + g * 5)) * BTILE
              + (size_t)sn * 1024 + (size_t)lane * 16;

    const float* bwr = bw + (size_t)o * IN_F + i0;
    float4 b0 = *(const float4*)bwr;
    float4 b1 = *(const float4*)(bwr + 4);
    float v[8] = {b0.x, b0.y, b0.z, b0.w, b1.x, b1.y, b1.z, b1.w};
    u16x8 s0;
    #pragma unroll
    for (int j = 0; j < 8; ++j) s0[j] = f2bf(v[j]);
    *(u16x8*)(Bt + tb) = s0;                        // s = 0

    float c[8][5];
    #pragma unroll
    for (int j = 0; j < 8; ++j) {
        const float* swr = sw + ((size_t)o * IN_F + i0 + j) * 8;
        float4 lo = *(const float4*)swr;
        float4 hi = *(const float4*)(swr + 4);
        c[j][0] = lo.x; c[j][1] = lo.y; c[j][2] = lo.z;
        c[j][3] = lo.w; c[j][4] = hi.x;
    }
    #pragma unroll
    for (int s = 1; s < 5; ++s) {
        u16x8 d;
        #pragma unroll
        for (int j = 0; j < 8; ++j) d[j] = f2bf(c[j][s] - c[j][s - 1]);
        *(u16x8*)(Bt + tb + (size_t)s * BTILE) = d;
    }
}

// ---------------------------------------------------------------------------
// bias[o] = sum_i sw[o,i,0]; plus 4 x-space step thresholds: smallest f32 T
// with (x >= T) <=> ((double)x > atanh(midpoint(grid[s], prevfloat(grid[s])))),
// replicating a correctly-rounded tanh's interval comparisons.
// ---------------------------------------------------------------------------
__global__ __launch_bounds__(256) void bias_thresh_kernel(
    const float* __restrict__ sw, const float* __restrict__ grid,
    float* __restrict__ biasT)
{
    int o    = blockIdx.x * 4 + (threadIdx.x >> 6);
    int lane = threadIdx.x & 63;
    float s = 0.f;
    #pragma unroll
    for (int j = 0; j < 16; ++j)
        s += sw[((size_t)o * IN_F + j * 64 + lane) * 8];
    #pragma unroll
    for (int off = 32; off; off >>= 1)
        s += __shfl_down(s, off);
    if (lane == 0) biasT[o] = s;

    if (blockIdx.x == 0 && threadIdx.x == 0) {
        #pragma unroll
        for (int k = 0; k < 4; ++k) {
            float gv = grid[k + 1];                 // -0.6, -0.2, 0.2, 0.6
            float below = nextafterf(gv, -2.0f);
            double mid = 0.5 * ((double)gv + (double)below);
            double t = atanh(mid);
            float Tf = (float)t;
            if (!((double)Tf > t)) Tf = nextafterf(Tf, 3.0f);
            biasT[1024 + k] = Tf;
        }
    }
}

// ---------------------------------------------------------------------------
// Fused GEMM: C = [bf16(x) | 1[x>=T_s]] @ B^T + bias.
// 1024 blocks (4/CU, 16 waves/CU) x 256 threads; block = 128 rows x 64 cols;
// wave = 64x32 out = 4x2 frags. One barrier per g-group: stage 5 tiles of
// g+1 (5 gload16/thread), compute 5 slabs barrier-free, vmcnt(8) leaves the
// 8 x-loads in flight, s_barrier. Wave slab order staggered by wave-id.
// ---------------------------------------------------------------------------
__device__ __forceinline__ void load_x(const float* xb, int g, float xc[4][8]) {
    #pragma unroll
    for (int m = 0; m < 4; ++m) {
        const float* p = xb + (size_t)m * 16 * IN_F + g * 32;
        float4 a = *(const float4*)p;
        float4 b = *(const float4*)(p + 4);
        xc[m][0] = a.x; xc[m][1] = a.y; xc[m][2] = a.z; xc[m][3] = a.w;
        xc[m][4] = b.x; xc[m][5] = b.y; xc[m][6] = b.z; xc[m][7] = b.w;
    }
}

__device__ __forceinline__ void build_af_cvt(const float xc[4][8], bf16x8 af[4]) {
    #pragma unroll
    for (int m = 0; m < 4; ++m) {
        union { u32 u[4]; bf16x8 v; } t;
        #pragma unroll
        for (int p = 0; p < 4; ++p)
            t.u[p] = cvt_pk(xc[m][2 * p], xc[m][2 * p + 1]);
        af[m] = t.v;
    }
}

__device__ __forceinline__ void build_af_ind(const float xc[4][8], float T,
                                             bf16x8 af[4]) {
    #pragma unroll
    for (int m = 0; m < 4; ++m) {
        union { u32 u[4]; bf16x8 v; } t;
        #pragma unroll
        for (int p = 0; p < 4; ++p)
            t.u[p] = cvt_pk(xc[m][2 * p]     >= T ? 1.0f : 0.0f,
                            xc[m][2 * p + 1] >= T ? 1.0f : 0.0f);
        af[m] = t.v;
    }
}

__device__ __forceinline__ void mfma_step(const char* slotbase, int wc, int lane,
                                          const bf16x8 af[4], f32x4 acc[4][2]) {
    bf16x8 bf[2];
    #pragma unroll
    for (int n = 0; n < 2; ++n)
        bf[n] = *(const bf16x8*)(slotbase + (wc * 2 + n) * 1024 + lane * 16);
    __builtin_amdgcn_s_setprio(1);
    #pragma unroll
    for (int m = 0; m < 4; ++m)
        #pragma unroll
        for (int n = 0; n < 2; ++n)
            acc[m][n] = __builtin_amdgcn_mfma_f32_16x16x32_bf16(
                af[m], bf[n], acc[m][n], 0, 0, 0);
    __builtin_amdgcn_s_setprio(0);
}

#define WAITV(N) asm volatile("s_waitcnt vmcnt(" #N ")" ::: "memory")

__global__ __launch_bounds__(256, 4) void gemm_kernel(
    const float* __restrict__ x, const char* __restrict__ Bt,
    const float* __restrict__ biasT, float* __restrict__ C)
{
    __shared__ __align__(16) char lds[2 * GBYTES]; // 40 KB: 2 g-group buffers

    int tid = threadIdx.x;
    int bid = blockIdx.x;                           // 0..1023

    int xcd  = bid & 7;
    int bcol = xcd * 2 + ((bid >> 3) & 1);          // 0..15; 2 panels per XCD
    int brow = bid >> 4;                            // 0..63

    int lane = tid & 63;
    int w    = tid >> 6;                            // 0..3
    int wr   = w >> 1;
    int wc   = w & 1;
    int fr   = lane & 15;
    int q    = lane >> 4;

    // thresholds rotated by wave-id (phase stagger); matching tile offsets
    float u0 = biasT[1024], u1 = biasT[1025], u2 = biasT[1026], u3 = biasT[1027];
    if (w & 1) { float t = u0; u0 = u1; u1 = u2; u2 = u3; u3 = t; }
    if (w & 2) { float t0 = u0, t1 = u1; u0 = u2; u1 = u3; u2 = t0; u3 = t1; }
    int o0 = (1 + ((0 + w) & 3)) * BTILE;
    int o1 = (1 + ((1 + w) & 3)) * BTILE;
    int o2 = (1 + ((2 + w) & 3)) * BTILE;
    int o3 = (1 + ((3 + w) & 3)) * BTILE;

    const float* xb  = x + (size_t)(brow * 128 + wr * 64 + fr) * IN_F + q * 8;
    const char* ssrc = Bt + (size_t)bcol * NSTEP * BTILE + (size_t)tid * 16;
    char*       sdst = lds + (size_t)tid * 16;

    int ccol0 = bcol * 64 + wc * 32 + fr;

    f32x4 acc[4][2];
    #pragma unroll
    for (int n = 0; n < 2; ++n) {
        float bv = biasT[ccol0 + n * 16];
        #pragma unroll
        for (int m = 0; m < 4; ++m)
            #pragma unroll
            for (int j = 0; j < 4; ++j)
                acc[m][n][j] = bv;
    }

    // stage all 5 tiles of g-group G into buffer BUF (5 x 16B per thread)
    #define STAGE_G(G, BUF) do {                                              \
        const char* _s = ssrc + (size_t)(5 * (G)) * BTILE;                    \
        char* _d = sdst + (size_t)(BUF) * GBYTES;                             \
        _Pragma("unroll")                                                     \
        for (int _t = 0; _t < 5; ++_t)                                        \
            gload16(_s + _t * BTILE, _d + _t * BTILE);                        \
    } while (0)

    // compute 5 slabs of group in BUF; reload xc for group GN at last use
    #define COMPUTE5(BUF, RELOAD, GN) do {                                    \
        const char* _b = lds + (size_t)(BUF) * GBYTES;                        \
        bf16x8 af[4];                                                         \
        build_af_cvt(xc, af);      mfma_step(_b,      wc, lane, af, acc);     \
        build_af_ind(xc, u0, af);  mfma_step(_b + o0, wc, lane, af, acc);     \
        build_af_ind(xc, u1, af);  mfma_step(_b + o1, wc, lane, af, acc);     \
        build_af_ind(xc, u2, af);  mfma_step(_b + o2, wc, lane, af, acc);     \
        build_af_ind(xc, u3, af);                                             \
        if (RELOAD) load_x(xb, (GN), xc);                                     \
        mfma_step(_b + o3, wc, lane, af, acc);                                \
    } while (0)

    float xc[4][8];

    // prologue
    load_x(xb, 0, xc);
    STAGE_G(0, 0);
    WAITV(0);
    __builtin_amdgcn_s_barrier();

    #pragma unroll 1
    for (int g = 0; g < 31; ++g) {
        STAGE_G(g + 1, (g + 1) & 1);
        __builtin_amdgcn_sched_barrier(0);          // pin: stages issued first
        COMPUTE5(g & 1, 1, g + 1);                  // 5 stage + 8 x in flight
        WAITV(8);                                   // drain stages, keep x
        __builtin_amdgcn_s_barrier();
    }
    COMPUTE5(1, 0, 0);                              // g = 31, buffer 1

    // epilogue: C/D layout col = lane&15, row = (lane>>4)*4 + reg (bias in acc)
    int crow0 = brow * 128 + wr * 64 + (q << 2);
    #pragma unroll
    for (int m = 0; m < 4; ++m)
        #pragma unroll
        for (int j = 0; j < 4; ++j) {
            size_t r = (size_t)(crow0 + m * 16 + j);
            float* cp = C + r * OUT_F + ccol0;
            #pragma unroll
            for (int n = 0; n < 2; ++n)
                cp[n * 16] = acc[m][n][j];
        }
    #undef STAGE_G
    #undef COMPUTE5
}

// Fallback signal if workspace is too small: absmax will read ~12345.
__global__ void sentinel_kernel(float* out, int n) {
    int i = blockIdx.x * 256 + threadIdx.x;
    if (i < n) out[i] = (i == 0) ? 12345.0f : 0.0f;
}

extern "C" void kernel_launch(void* const* d_in, const int* in_sizes, int n_in,
                              void* d_out, int out_size, void* d_ws, size_t ws_size,
                              hipStream_t stream) {
    const float* x    = (const float*)d_in[0];
    const float* sw   = (const float*)d_in[1];
    const float* bw   = (const float*)d_in[2];
    const float* grid = (const float*)d_in[3];
    float* out = (float*)d_out;

    const size_t B_bytes = (size_t)16 * NSTEP * BTILE;  // 10,485,760
    const size_t bias_bytes = (1024 + 4) * sizeof(float);
    if (ws_size < B_bytes + bias_bytes) {
        sentinel_kernel<<<(out_size + 255) / 256, 256, 0, stream>>>(out, out_size);
        return;
    }

    char*  Bt    = (char*)d_ws;
    float* biasT = (float*)((char*)d_ws + B_bytes);

    bias_thresh_kernel<<<256, 256, 0, stream>>>(sw, grid, biasT);
    pack_B_kernel<<<512, 256, 0, stream>>>(sw, bw, Bt);
    gemm_kernel<<<1024, 256, 0, stream>>>(x, Bt, biasT, out);
}

// Round 10
// 133.959 us; speedup vs baseline: 1.3251x; 1.3251x over previous
//
#include <hip/hip_runtime.h>
#include <hip/hip_bf16.h>
#include <math.h>

#define B_DIM 8192
#define IN_F  1024
#define OUT_F 1024
#define NSTEP 160                    // 32 g-groups x 5 slabs (K=5120)
#define BTILE 8192                   // one B step-tile: 128 cols x 32 k x 2B

typedef unsigned short u16;
typedef unsigned int u32;
typedef __attribute__((ext_vector_type(8))) short bf16x8;
typedef __attribute__((ext_vector_type(8))) unsigned short u16x8;
typedef __attribute__((ext_vector_type(4))) float f32x4;

#define GLOBAL_AS __attribute__((address_space(1)))
#define LDS_AS    __attribute__((address_space(3)))

__device__ __forceinline__ void gload16(const void* g, void* l) {
    __builtin_amdgcn_global_load_lds((const GLOBAL_AS unsigned int*)g,
                                     (LDS_AS unsigned int*)l, 16, 0, 0);
}

__device__ __forceinline__ u16 f2bf(float v) {
    u32 u = __float_as_uint(v);
    return (u16)((u + 0x7FFFu + ((u >> 16) & 1u)) >> 16);
}

__device__ __forceinline__ u32 cvt_pk(float lo, float hi) {
    u32 r;
    asm("v_cvt_pk_bf16_f32 %0, %1, %2" : "=v"(r) : "v"(lo), "v"(hi));
    return r;
}

// ---------------------------------------------------------------------------
// B image, 8 panels of 128 cols, ordered by GEMM step t = g*5 + s:
//   s=0: bf16(base_weight), s=1..4: bf16(sw_s - sw_{s-1}).
// Tile byte = ((p*160 + g*5 + s)*8192) + sn*1024 + lane*16. Every GEMM-side
// access (gload_lds dst/src and ds_read_b128) is base + lane*16.
// ---------------------------------------------------------------------------
__global__ __launch_bounds__(256) void pack_B_kernel(
    const float* __restrict__ sw, const float* __restrict__ bw,
    char* __restrict__ Bt)
{
    int gid  = blockIdx.x * 256 + threadIdx.x;      // 131072 threads
    int lane = gid & 63;
    int wav  = gid >> 6;                            // 2048 waves
    int g    = wav & 31;
    int sn   = (wav >> 5) & 7;
    int p    = wav >> 8;                            // 0..7
    int fc   = lane & 15;
    int q    = lane >> 4;

    int o  = p * 128 + sn * 16 + fc;
    int i0 = g * 32 + q * 8;

    size_t tb = ((size_t)(p * 160 + g * 5)) * BTILE
              + (size_t)sn * 1024 + (size_t)lane * 16;

    const float* bwr = bw + (size_t)o * IN_F + i0;
    float4 b0 = *(const float4*)bwr;
    float4 b1 = *(const float4*)(bwr + 4);
    float v[8] = {b0.x, b0.y, b0.z, b0.w, b1.x, b1.y, b1.z, b1.w};
    u16x8 s0;
    #pragma unroll
    for (int j = 0; j < 8; ++j) s0[j] = f2bf(v[j]);
    *(u16x8*)(Bt + tb) = s0;                        // s = 0

    float c[8][5];
    #pragma unroll
    for (int j = 0; j < 8; ++j) {
        const float* swr = sw + ((size_t)o * IN_F + i0 + j) * 8;
        float4 lo = *(const float4*)swr;
        float4 hi = *(const float4*)(swr + 4);
        c[j][0] = lo.x; c[j][1] = lo.y; c[j][2] = lo.z;
        c[j][3] = lo.w; c[j][4] = hi.x;
    }
    #pragma unroll
    for (int s = 1; s < 5; ++s) {
        u16x8 d;
        #pragma unroll
        for (int j = 0; j < 8; ++j) d[j] = f2bf(c[j][s] - c[j][s - 1]);
        *(u16x8*)(Bt + tb + (size_t)s * BTILE) = d;
    }
}

// ---------------------------------------------------------------------------
// bias[o] = sum_i sw[o,i,0]; plus 4 x-space step thresholds: smallest f32 T
// with (x >= T) <=> ((double)x > atanh(midpoint(grid[s], prevfloat(grid[s])))),
// replicating a correctly-rounded tanh's interval comparisons.
// ---------------------------------------------------------------------------
__global__ __launch_bounds__(256) void bias_thresh_kernel(
    const float* __restrict__ sw, const float* __restrict__ grid,
    float* __restrict__ biasT)
{
    int o    = blockIdx.x * 4 + (threadIdx.x >> 6);
    int lane = threadIdx.x & 63;
    float s = 0.f;
    #pragma unroll
    for (int j = 0; j < 16; ++j)
        s += sw[((size_t)o * IN_F + j * 64 + lane) * 8];
    #pragma unroll
    for (int off = 32; off; off >>= 1)
        s += __shfl_down(s, off);
    if (lane == 0) biasT[o] = s;

    if (blockIdx.x == 0 && threadIdx.x == 0) {
        #pragma unroll
        for (int k = 0; k < 4; ++k) {
            float gv = grid[k + 1];                 // -0.6, -0.2, 0.2, 0.6
            float below = nextafterf(gv, -2.0f);
            double mid = 0.5 * ((double)gv + (double)below);
            double t = atanh(mid);
            float Tf = (float)t;
            if (!((double)Tf > t)) Tf = nextafterf(Tf, 3.0f);
            biasT[1024 + k] = Tf;
        }
    }
}

// ---------------------------------------------------------------------------
// Fused GEMM: C = [bf16(x) | 1[x>=T_s]] @ B^T + bias.
// 1024 blocks (4/CU, 16 waves/CU) x 256 threads; block = 64 rows x 128 cols;
// wave = 32x64 out = 2x4 frags (acc 32 + xc 16 VGPR -> fits 128-reg budget).
// B: 4-slot x 8KB LDS ring, stage(t+3) per tile, counted vmcnt {4,4,8,8,8}
// (x reload at s=2 folded into the count); one s_barrier per tile — cheap at
// 4 blocks/CU since other blocks' waves fill the bubble.
// ---------------------------------------------------------------------------
__device__ __forceinline__ void load_x(const float* xb, int g, float xc[2][8]) {
    #pragma unroll
    for (int m = 0; m < 2; ++m) {
        const float* p = xb + (size_t)m * 16 * IN_F + g * 32;
        float4 a = *(const float4*)p;
        float4 b = *(const float4*)(p + 4);
        xc[m][0] = a.x; xc[m][1] = a.y; xc[m][2] = a.z; xc[m][3] = a.w;
        xc[m][4] = b.x; xc[m][5] = b.y; xc[m][6] = b.z; xc[m][7] = b.w;
    }
}

__device__ __forceinline__ void build_af_cvt(const float xc[2][8], bf16x8 af[2]) {
    #pragma unroll
    for (int m = 0; m < 2; ++m) {
        union { u32 u[4]; bf16x8 v; } t;
        #pragma unroll
        for (int p = 0; p < 4; ++p)
            t.u[p] = cvt_pk(xc[m][2 * p], xc[m][2 * p + 1]);
        af[m] = t.v;
    }
}

__device__ __forceinline__ void build_af_ind(const float xc[2][8], float T,
                                             bf16x8 af[2]) {
    #pragma unroll
    for (int m = 0; m < 2; ++m) {
        union { u32 u[4]; bf16x8 v; } t;
        #pragma unroll
        for (int p = 0; p < 4; ++p)
            t.u[p] = cvt_pk(xc[m][2 * p]     >= T ? 1.0f : 0.0f,
                            xc[m][2 * p + 1] >= T ? 1.0f : 0.0f);
        af[m] = t.v;
    }
}

__device__ __forceinline__ void mfma8(const char* base, int wc, int lane,
                                      const bf16x8 af[2], f32x4 acc[2][4]) {
    bf16x8 bf[4];
    #pragma unroll
    for (int n = 0; n < 4; ++n)
        bf[n] = *(const bf16x8*)(base + (wc * 4 + n) * 1024 + lane * 16);
    __builtin_amdgcn_s_setprio(1);
    #pragma unroll
    for (int m = 0; m < 2; ++m)
        #pragma unroll
        for (int n = 0; n < 4; ++n)
            acc[m][n] = __builtin_amdgcn_mfma_f32_16x16x32_bf16(
                af[m], bf[n], acc[m][n], 0, 0, 0);
    __builtin_amdgcn_s_setprio(0);
}

#define WAITV_(N) asm volatile("s_waitcnt vmcnt(" #N ")" ::: "memory")
#define WAITV(N)  WAITV_(N)

__global__ __launch_bounds__(256, 4) void gemm_kernel(
    const float* __restrict__ x, const char* __restrict__ Bt,
    const float* __restrict__ biasT, float* __restrict__ C)
{
    __shared__ __align__(16) char lds[32768];       // 4-slot B ring

    int tid = threadIdx.x;
    int bid = blockIdx.x;                           // 0..1023

    int bcol = bid & 7;                             // == XCD (panel L2-pinned)
    int brow = bid >> 3;                            // 0..127 (64-row panels)

    int lane = tid & 63;
    int w    = tid >> 6;                            // 0..3
    int wr   = w >> 1;                              // 32-row half
    int wc   = w & 1;                               // 64-col half
    int fr   = lane & 15;
    int q    = lane >> 4;

    float u0 = biasT[1024], u1 = biasT[1025], u2 = biasT[1026], u3 = biasT[1027];

    const float* xb = x + (size_t)(brow * 64 + wr * 32 + fr) * IN_F + q * 8;
    const char*  sp = Bt + (size_t)bcol * NSTEP * BTILE + (size_t)tid * 16;
    char*      sdst = lds + (size_t)tid * 16;

    int ccol0 = bcol * 128 + wc * 64 + fr;

    f32x4 acc[2][4];
    #pragma unroll
    for (int n = 0; n < 4; ++n) {
        float bv = biasT[ccol0 + n * 16];
        #pragma unroll
        for (int m = 0; m < 2; ++m)
            #pragma unroll
            for (int j = 0; j < 4; ++j)
                acc[m][n][j] = bv;
    }

    float xc[2][8];
    bf16x8 af[2];
    int cs = 0;                                     // compute-slot byte offset

    // prologue: stage tiles 0,1,2 into slots 0,1,2; load x(0)
    gload16(sp,                sdst);
    gload16(sp + 4096,         sdst + 4096);
    gload16(sp + BTILE,        sdst + 8192);
    gload16(sp + BTILE + 4096, sdst + 8192 + 4096);
    gload16(sp + 2 * BTILE,        sdst + 16384);
    gload16(sp + 2 * BTILE + 4096, sdst + 16384 + 4096);
    load_x(xb, 0, xc);
    sp += 3 * BTILE;
    WAITV(8);                                       // tile 0 landed
    __builtin_amdgcn_s_barrier();

    // per-tile phase: stage(t+3), optional x reload, build, 8 MFMA,
    // counted vmcnt, barrier. Slot of t+3 = cs + 24 KB (mod 32 KB).
    #define PHASE(BUILDER, WN)                                               \
        do {                                                                 \
            int ss = (cs + 24576) & 32767;                                   \
            gload16(sp, sdst + ss); gload16(sp + 4096, sdst + ss + 4096);    \
            sp += BTILE;                                                     \
            __builtin_amdgcn_sched_barrier(0);                               \
            BUILDER;                                                         \
            mfma8(lds + cs, wc, lane, af, acc);                              \
            WAITV(WN); __builtin_amdgcn_s_barrier();                         \
            cs = (cs + 8192) & 32767;                                        \
        } while (0)

    #define PHASE_X(BUILDER, WN, GN)                                         \
        do {                                                                 \
            int ss = (cs + 24576) & 32767;                                   \
            gload16(sp, sdst + ss); gload16(sp + 4096, sdst + ss + 4096);    \
            sp += BTILE;                                                     \
            load_x(xb, (GN), xc2);                                           \
            __builtin_amdgcn_sched_barrier(0);                               \
            BUILDER;                                                         \
            mfma8(lds + cs, wc, lane, af, acc);                              \
            WAITV(WN); __builtin_amdgcn_s_barrier();                         \
            cs = (cs + 8192) & 32767;                                        \
        } while (0)

    float xc2[2][8];                                // x double-buffer

    #pragma unroll 1
    for (int g = 0; g < 31; ++g) {
        // s0..s4 of group g; x(g+1) prefetched at s2 into xc2, swapped at end
        PHASE (build_af_cvt(xc, af),     4);
        PHASE (build_af_ind(xc, u0, af), 4);
        PHASE_X(build_af_ind(xc, u1, af), 8, g + 1);
        PHASE (build_af_ind(xc, u2, af), 8);
        PHASE (build_af_ind(xc, u3, af), 8);
        #pragma unroll
        for (int m = 0; m < 2; ++m)
            #pragma unroll
            for (int j = 0; j < 8; ++j)
                xc[m][j] = xc2[m][j];
    }

    // tail g = 31: tiles 155..159; stage only 158,159; drain waits 4,4,2,0
    {
        int ss = (cs + 24576) & 32767;
        gload16(sp, sdst + ss); gload16(sp + 4096, sdst + ss + 4096);
        sp += BTILE;
        build_af_cvt(xc, af);
        mfma8(lds + cs, wc, lane, af, acc);
        WAITV(4); __builtin_amdgcn_s_barrier();
        cs = (cs + 8192) & 32767;

        ss = (cs + 24576) & 32767;
        gload16(sp, sdst + ss); gload16(sp + 4096, sdst + ss + 4096);
        build_af_ind(xc, u0, af);
        mfma8(lds + cs, wc, lane, af, acc);
        WAITV(4); __builtin_amdgcn_s_barrier();
        cs = (cs + 8192) & 32767;

        build_af_ind(xc, u1, af);
        mfma8(lds + cs, wc, lane, af, acc);
        WAITV(2); __builtin_amdgcn_s_barrier();
        cs = (cs + 8192) & 32767;

        build_af_ind(xc, u2, af);
        mfma8(lds + cs, wc, lane, af, acc);
        WAITV(0); __builtin_amdgcn_s_barrier();
        cs = (cs + 8192) & 32767;

        build_af_ind(xc, u3, af);
        mfma8(lds + cs, wc, lane, af, acc);
    }
    #undef PHASE
    #undef PHASE_X

    // epilogue: C/D layout col = lane&15, row = (lane>>4)*4 + reg (bias in acc)
    int crow0 = brow * 64 + wr * 32 + (q << 2);
    #pragma unroll
    for (int m = 0; m < 2; ++m)
        #pragma unroll
        for (int j = 0; j < 4; ++j) {
            size_t r = (size_t)(crow0 + m * 16 + j);
            float* cp = C + r * OUT_F + ccol0;
            #pragma unroll
            for (int n = 0; n < 4; ++n)
                cp[n * 16] = acc[m][n][j];
        }
}

// Fallback signal if workspace is too small: absmax will read ~12345.
__global__ void sentinel_kernel(float* out, int n) {
    int i = blockIdx.x * 256 + threadIdx.x;
    if (i < n) out[i] = (i == 0) ? 12345.0f : 0.0f;
}

extern "C" void kernel_launch(void* const* d_in, const int* in_sizes, int n_in,
                              void* d_out, int out_size, void* d_ws, size_t ws_size,
                              hipStream_t stream) {
    const float* x    = (const float*)d_in[0];
    const float* sw   = (const float*)d_in[1];
    const float* bw   = (const float*)d_in[2];
    const float* grid = (const float*)d_in[3];
    float* out = (float*)d_out;

    const size_t B_bytes = (size_t)8 * NSTEP * BTILE;   // 10,485,760
    const size_t bias_bytes = (1024 + 4) * sizeof(float);
    if (ws_size < B_bytes + bias_bytes) {
        sentinel_kernel<<<(out_size + 255) / 256, 256, 0, stream>>>(out, out_size);
        return;
    }

    char*  Bt    = (char*)d_ws;
    float* biasT = (float*)((char*)d_ws + B_bytes);

    bias_thresh_kernel<<<256, 256, 0, stream>>>(sw, grid, biasT);
    pack_B_kernel<<<512, 256, 0, stream>>>(sw, bw, Bt);
    gemm_kernel<<<1024, 256, 0, stream>>>(x, Bt, biasT, out);
}

// Round 11
// 115.234 us; speedup vs baseline: 1.5405x; 1.1625x over previous
//
#include <hip/hip_runtime.h>
#include <hip/hip_bf16.h>
#include <math.h>

#define B_DIM 8192
#define IN_F  1024
#define OUT_F 1024
#define NSTEP 160                    // 32 g-groups x 5 slabs (K=5120)
#define BTILE 8192                   // one step-tile: 128 rows/cols x 32 k x 2B

typedef unsigned short u16;
typedef unsigned int u32;
typedef __attribute__((ext_vector_type(8))) short bf16x8;
typedef __attribute__((ext_vector_type(8))) unsigned short u16x8;
typedef __attribute__((ext_vector_type(4))) float f32x4;

#define GLOBAL_AS __attribute__((address_space(1)))
#define LDS_AS    __attribute__((address_space(3)))

__device__ __forceinline__ void gload16(const void* g, void* l) {
    __builtin_amdgcn_global_load_lds((const GLOBAL_AS unsigned int*)g,
                                     (LDS_AS unsigned int*)l, 16, 0, 0);
}

__device__ __forceinline__ u16 f2bf(float v) {
    u32 u = __float_as_uint(v);
    return (u16)((u + 0x7FFFu + ((u >> 16) & 1u)) >> 16);
}

__device__ __forceinline__ u32 cvt_pk(float lo, float hi) {
    u32 r;
    asm("v_cvt_pk_bf16_f32 %0, %1, %2" : "=v"(r) : "v"(lo), "v"(hi));
    return r;
}

// ---------------------------------------------------------------------------
// bias[o] = sum_i sw[o,i,0]; plus 4 x-space step thresholds: smallest f32 T
// with (x >= T) <=> ((double)x > atanh(midpoint(grid[s], prevfloat(grid[s])))),
// replicating a correctly-rounded tanh's interval comparisons.
// Runs FIRST: pack_A and gemm read biasT.
// ---------------------------------------------------------------------------
__global__ __launch_bounds__(256) void bias_thresh_kernel(
    const float* __restrict__ sw, const float* __restrict__ grid,
    float* __restrict__ biasT)
{
    int o    = blockIdx.x * 4 + (threadIdx.x >> 6);
    int lane = threadIdx.x & 63;
    float s = 0.f;
    #pragma unroll
    for (int j = 0; j < 16; ++j)
        s += sw[((size_t)o * IN_F + j * 64 + lane) * 8];
    #pragma unroll
    for (int off = 32; off; off >>= 1)
        s += __shfl_down(s, off);
    if (lane == 0) biasT[o] = s;

    if (blockIdx.x == 0 && threadIdx.x == 0) {
        #pragma unroll
        for (int k = 0; k < 4; ++k) {
            float gv = grid[k + 1];                 // -0.6, -0.2, 0.2, 0.6
            float below = nextafterf(gv, -2.0f);
            double mid = 0.5 * ((double)gv + (double)below);
            double t = atanh(mid);
            float Tf = (float)t;
            if (!((double)Tf > t)) Tf = nextafterf(Tf, 3.0f);
            biasT[1024 + k] = Tf;
        }
    }
}

// ---------------------------------------------------------------------------
// pack_A: 64 panels of 128 rows; tiles ordered t = g*5 + s.
//   s=0: bf16(x); s=1..4: 1[x >= T_s] as bf16 {0,1}.
// Tile byte = ((p*160 + t)*8192) + sm*1024 + lane*16, lane -> (fr,q).
// One wave per (p,sm,g): 5 contiguous 1KB wave-chunk stores.
// ---------------------------------------------------------------------------
__global__ __launch_bounds__(256) void pack_A_kernel(
    const float* __restrict__ x, const float* __restrict__ biasT,
    char* __restrict__ A)
{
    int gid  = blockIdx.x * 256 + threadIdx.x;      // 1,048,576 threads
    int lane = gid & 63;
    int wav  = gid >> 6;                            // 16384 waves
    int g    = wav & 31;
    int sm   = (wav >> 5) & 7;
    int p    = wav >> 8;                            // 0..63
    int fr   = lane & 15;
    int q    = lane >> 4;

    float T1 = biasT[1024], T2 = biasT[1025], T3 = biasT[1026], T4 = biasT[1027];

    int b  = p * 128 + sm * 16 + fr;
    int i0 = g * 32 + q * 8;

    const float* xr = x + (size_t)b * IN_F + i0;
    float4 a0 = *(const float4*)xr;
    float4 a1 = *(const float4*)(xr + 4);
    float v[8] = {a0.x, a0.y, a0.z, a0.w, a1.x, a1.y, a1.z, a1.w};

    size_t tb = ((size_t)(p * NSTEP + g * 5)) * BTILE
              + (size_t)sm * 1024 + (size_t)lane * 16;

    // s = 0: bf16(x)
    {
        union { u32 u[4]; u16x8 s; } w;
        #pragma unroll
        for (int j = 0; j < 4; ++j) w.u[j] = cvt_pk(v[2 * j], v[2 * j + 1]);
        *(u16x8*)(A + tb) = w.s;
    }
    // s = 1..4: step indicators
    float T[4] = {T1, T2, T3, T4};
    #pragma unroll
    for (int s = 0; s < 4; ++s) {
        union { u32 u[4]; u16x8 t; } o;
        #pragma unroll
        for (int j = 0; j < 4; ++j)
            o.u[j] = (v[2 * j]     >= T[s] ? 0x00003F80u : 0u)
                   | (v[2 * j + 1] >= T[s] ? 0x3F800000u : 0u);
        *(u16x8*)(A + tb + (size_t)(s + 1) * BTILE) = o.t;
    }
}

// ---------------------------------------------------------------------------
// pack_B: 8 panels of 128 cols; tiles ordered t = g*5 + s.
//   s=0: bf16(base_weight); s=1..4: bf16(sw_s - sw_{s-1}).
// ---------------------------------------------------------------------------
__global__ __launch_bounds__(256) void pack_B_kernel(
    const float* __restrict__ sw, const float* __restrict__ bw,
    char* __restrict__ Bt)
{
    int gid  = blockIdx.x * 256 + threadIdx.x;      // 131072 threads
    int lane = gid & 63;
    int wav  = gid >> 6;                            // 2048 waves
    int g    = wav & 31;
    int sn   = (wav >> 5) & 7;
    int p    = wav >> 8;                            // 0..7
    int fc   = lane & 15;
    int q    = lane >> 4;

    int o  = p * 128 + sn * 16 + fc;
    int i0 = g * 32 + q * 8;

    size_t tb = ((size_t)(p * NSTEP + g * 5)) * BTILE
              + (size_t)sn * 1024 + (size_t)lane * 16;

    const float* bwr = bw + (size_t)o * IN_F + i0;
    float4 b0 = *(const float4*)bwr;
    float4 b1 = *(const float4*)(bwr + 4);
    float v[8] = {b0.x, b0.y, b0.z, b0.w, b1.x, b1.y, b1.z, b1.w};
    u16x8 s0;
    #pragma unroll
    for (int j = 0; j < 8; ++j) s0[j] = f2bf(v[j]);
    *(u16x8*)(Bt + tb) = s0;                        // s = 0

    float c[8][5];
    #pragma unroll
    for (int j = 0; j < 8; ++j) {
        const float* swr = sw + ((size_t)o * IN_F + i0 + j) * 8;
        float4 lo = *(const float4*)swr;
        float4 hi = *(const float4*)(swr + 4);
        c[j][0] = lo.x; c[j][1] = lo.y; c[j][2] = lo.z;
        c[j][3] = lo.w; c[j][4] = hi.x;
    }
    #pragma unroll
    for (int s = 1; s < 5; ++s) {
        u16x8 d;
        #pragma unroll
        for (int j = 0; j < 8; ++j) d[j] = f2bf(c[j][s] - c[j][s - 1]);
        *(u16x8*)(Bt + tb + (size_t)s * BTILE) = d;
    }
}

// ---------------------------------------------------------------------------
// GEMM (R3 structure, measured 99.7us @192 tiles; now 160 tiles):
// C[8192,1024] f32 = A @ B^T + bias. 128x128 tile, BK=32 per step-tile,
// 4-buffer LDS ring (64 KB), depth-3 prefetch, counted vmcnt (never 0 in
// steady state), one raw s_barrier per tile, setprio around MFMA cluster.
// 4 waves 2x2; wave = 64x64 out = 4x4 frags of 16x16.
// ---------------------------------------------------------------------------
__device__ __forceinline__ void stage_tile(const char* Ap, const char* Bp,
                                           int t, char* buf, int tid) {
    const char* sa = Ap + (size_t)t * BTILE;
    const char* sb = Bp + (size_t)t * BTILE;
    gload16(sa + tid * 16,        buf + tid * 16);
    gload16(sa + tid * 16 + 4096, buf + tid * 16 + 4096);
    gload16(sb + tid * 16,        buf + 8192 + tid * 16);
    gload16(sb + tid * 16 + 4096, buf + 8192 + tid * 16 + 4096);
}

__device__ __forceinline__ void compute_tile(const char* buf, int lane,
                                             int wr, int wc, f32x4 acc[4][4]) {
    const u16* As = (const u16*)buf;
    const u16* Bs = As + 4096;                      // +8192 bytes
    bf16x8 af[4], bfv[4];
    #pragma unroll
    for (int m = 0; m < 4; ++m)
        af[m] = *(const bf16x8*)(As + (wr * 4 + m) * 512 + lane * 8);
    #pragma unroll
    for (int n = 0; n < 4; ++n)
        bfv[n] = *(const bf16x8*)(Bs + (wc * 4 + n) * 512 + lane * 8);

    __builtin_amdgcn_s_setprio(1);
    #pragma unroll
    for (int m = 0; m < 4; ++m)
        #pragma unroll
        for (int n = 0; n < 4; ++n)
            acc[m][n] = __builtin_amdgcn_mfma_f32_16x16x32_bf16(
                af[m], bfv[n], acc[m][n], 0, 0, 0);
    __builtin_amdgcn_s_setprio(0);
}

__global__ __launch_bounds__(256, 2) void gemm_kernel(
    const char* __restrict__ At, const char* __restrict__ Bt,
    const float* __restrict__ biasT, float* __restrict__ C)
{
    __shared__ __align__(16) char lds[4 * 16384];   // 4-buffer ring, 64 KB

    int tid = threadIdx.x;
    int bid = blockIdx.x;                           // 0..511

    // XCD swizzle: each XCD owns an 8x8 supertile of output tiles.
    int xcd  = bid & 7;
    int slot = bid >> 3;
    int tile = xcd * 64 + slot;
    int brow = tile >> 3;                           // 0..63
    int bcol = tile & 7;                            // 0..7

    int lane = tid & 63;
    int w    = tid >> 6;
    int wr   = w >> 1;
    int wc   = w & 1;

    const char* Ap = At + (size_t)brow * NSTEP * BTILE;
    const char* Bp = Bt + (size_t)bcol * NSTEP * BTILE;

    int ccol0 = bcol * 128 + wc * 64 + (lane & 15);

    f32x4 acc[4][4];
    #pragma unroll
    for (int n = 0; n < 4; ++n) {
        float bv = biasT[ccol0 + n * 16];
        #pragma unroll
        for (int m = 0; m < 4; ++m)
            #pragma unroll
            for (int j = 0; j < 4; ++j)
                acc[m][n][j] = bv;
    }

    // prologue: fill 3 ring slots (12 loads in flight)
    stage_tile(Ap, Bp, 0, lds,          tid);
    stage_tile(Ap, Bp, 1, lds + 16384,  tid);
    stage_tile(Ap, Bp, 2, lds + 32768,  tid);

    for (int t = 0; t < NSTEP; ++t) {
        // wait for stage(t): leave later stages' loads in flight
        if (t < NSTEP - 2)       asm volatile("s_waitcnt vmcnt(8)" ::: "memory");
        else if (t == NSTEP - 2) asm volatile("s_waitcnt vmcnt(4)" ::: "memory");
        else                     asm volatile("s_waitcnt vmcnt(0)" ::: "memory");
        __builtin_amdgcn_s_barrier();               // publishes stage(t); fences
        asm volatile("" ::: "memory");              // compute(t-1) vs stage(t+3)

        if (t + 3 < NSTEP)
            stage_tile(Ap, Bp, t + 3, lds + ((t + 3) & 3) * 16384, tid);

        compute_tile(lds + (t & 3) * 16384, lane, wr, wc, acc);
    }

    // epilogue: C/D layout col = lane&15, row = (lane>>4)*4 + reg (bias in acc)
    int crow0 = brow * 128 + wr * 64 + ((lane >> 4) << 2);
    #pragma unroll
    for (int m = 0; m < 4; ++m)
        #pragma unroll
        for (int j = 0; j < 4; ++j) {
            size_t r = (size_t)(crow0 + m * 16 + j);
            float* cp = C + r * OUT_F + ccol0;
            #pragma unroll
            for (int n = 0; n < 4; ++n)
                cp[n * 16] = acc[m][n][j];
        }
}

// Fallback signal if workspace is too small: absmax will read ~12345.
__global__ void sentinel_kernel(float* out, int n) {
    int i = blockIdx.x * 256 + threadIdx.x;
    if (i < n) out[i] = (i == 0) ? 12345.0f : 0.0f;
}

extern "C" void kernel_launch(void* const* d_in, const int* in_sizes, int n_in,
                              void* d_out, int out_size, void* d_ws, size_t ws_size,
                              hipStream_t stream) {
    const float* x    = (const float*)d_in[0];
    const float* sw   = (const float*)d_in[1];
    const float* bw   = (const float*)d_in[2];
    const float* grid = (const float*)d_in[3];
    float* out = (float*)d_out;

    const size_t A_bytes = (size_t)64 * NSTEP * BTILE;  // 83,886,080
    const size_t B_bytes = (size_t)8  * NSTEP * BTILE;  // 10,485,760
    const size_t bias_bytes = (1024 + 4) * sizeof(float);
    if (ws_size < A_bytes + B_bytes + bias_bytes) {
        sentinel_kernel<<<(out_size + 255) / 256, 256, 0, stream>>>(out, out_size);
        return;
    }

    char*  At    = (char*)d_ws;
    char*  Bt    = (char*)d_ws + A_bytes;
    float* biasT = (float*)((char*)d_ws + A_bytes + B_bytes);

    bias_thresh_kernel<<<256, 256, 0, stream>>>(sw, grid, biasT);
    pack_A_kernel<<<4096, 256, 0, stream>>>(x, biasT, At);
    pack_B_kernel<<<512, 256, 0, stream>>>(sw, bw, Bt);
    gemm_kernel<<<512, 256, 0, stream>>>(At, Bt, biasT, out);
}